// Round 6
// baseline (596.269 us; speedup 1.0000x reference)
//
#include <hip/hip_runtime.h>

// Problem constants (from reference): D=4, J=256, K=512, H=512, B=1024
#define J_ 256
#define K_ 512
#define H_ 512
#define B_ 1024

typedef float f32x4 __attribute__((ext_vector_type(4)));
typedef unsigned int u32x4 __attribute__((ext_vector_type(4)));
typedef unsigned short u16x4 __attribute__((ext_vector_type(4)));
typedef unsigned short u16x8 __attribute__((ext_vector_type(8)));
typedef __bf16 bf16x8 __attribute__((ext_vector_type(8)));

// f32 -> bf16 round-to-nearest-even (manual; inputs are finite)
__device__ __forceinline__ unsigned short f2bf(float f) {
    unsigned int u = __float_as_uint(f);
    u += 0x7fffu + ((u >> 16) & 1u);
    return (unsigned short)(u >> 16);
}

// async global->LDS, 16B per lane; LDS dest is wave-uniform base + lane*16
__device__ __forceinline__ void gload_lds16(const void* g, void* l) {
    __builtin_amdgcn_global_load_lds(
        (const __attribute__((address_space(1))) unsigned int*)g,
        (__attribute__((address_space(3))) unsigned int*)l, 16, 0, 0);
}

// Prep: x f32 -> bf16 into ws; init out: mu[b,j] = b1[j]; logvar tail.
__global__ __launch_bounds__(256) void prep_kernel(
    const float* __restrict__ x, const float* __restrict__ b1,
    const float* __restrict__ logvar, unsigned short* __restrict__ xbf,
    float* __restrict__ out) {
    int t = blockIdx.x * 256 + threadIdx.x;
    {
        f32x4 v = *(const f32x4*)(x + (size_t)t * 4);
        u16x4 o;
        o[0] = f2bf(v[0]); o[1] = f2bf(v[1]); o[2] = f2bf(v[2]); o[3] = f2bf(v[3]);
        *(u16x4*)(xbf + (size_t)t * 4) = o;
    }
    if (t < (B_ * J_) / 4) {
        int b = t >> 6;
        int j4 = (t & 63) << 2;
        f32x4 bb = *(const f32x4*)(b1 + j4);
        *(f32x4*)(out + ((size_t)b << 8) + j4) = bb;
    }
    if (t < 4) out[B_ * J_ + t] = logvar[t];
}

// W0' = bf16(W0 * wi), memory-bound pass.
__global__ __launch_bounds__(256) void wprep_kernel(
    const float* __restrict__ W0, const float* __restrict__ wmask,
    const int* __restrict__ ip, unsigned short* __restrict__ w0p) {
    size_t t = (size_t)blockIdx.x * 256 + threadIdx.x;
    size_t e = t * 8;
    int j = (int)(e >> 18);               // H*K = 262144 elems per j
    int k = (int)(e & (K_ - 1));
    const float* wi = wmask + ((size_t)ip[0] * J_ + j) * K_ + k;
    f32x4 s0 = *(const f32x4*)wi;
    f32x4 s1 = *(const f32x4*)(wi + 4);
    f32x4 a0 = *(const f32x4*)(W0 + e);
    f32x4 a1 = *(const f32x4*)(W0 + e + 4);
    a0 *= s0; a1 *= s1;
    u16x8 o;
    #pragma unroll
    for (int q = 0; q < 4; ++q) { o[q] = f2bf(a0[q]); o[q + 4] = f2bf(a1[q]); }
    *(u16x8*)(w0p + e) = o;
}

// Fine-interleaved pipelined grouped GEMM.
// Tile 256(M)x256(N), BK=32 (16 K-tiles), 512 thr = 8 waves (2M x 4N),
// wave tile 128x64. 4 LDS K-tile buffers (A 16KB + B 16KB each) = 128KB.
// Per K-tile: 2 phases; each phase: {stage 2 gloads | ds_read next-phase
// frags | 16 MFMA on current frags | lgkmcnt(0) | counted vmcnt | barrier}.
// vmcnt(6) steady state: loads stay in flight across barriers (T3+T4).
// Grid 2048 = j(256) x mb(4) x nb(2); 8 blocks of a j share one XCD.
__global__ __launch_bounds__(512, 2) void enc_kernel(
    const unsigned short* __restrict__ xbf,
    const unsigned short* __restrict__ w0p,
    const float* __restrict__ b0,
    const float* __restrict__ W1,
    float* __restrict__ out) {
    __shared__ unsigned char ldsA[4 * 16384];   // [buf][row 256][chunk 4 x 16B]
    __shared__ unsigned char ldsB[4 * 16384];

    int p = blockIdx.x;
    int xcd = p & 7;
    int t = p >> 3;                 // 0..255
    int j = (xcd << 5) + (t >> 3);
    int inner = t & 7;
    int m0 = (inner >> 1) << 8;     // 0,256,512,768
    int h0 = (inner & 1) << 8;      // 0,256

    int tid = threadIdx.x;
    int lane = tid & 63;
    int wv = tid >> 6;              // 0..7
    int wmv = wv >> 2;              // M-wave 0..1 (128 rows)
    int wnv = wv & 3;               // N-wave 0..3 (64 cols)
    int lr = lane & 15, lg = lane >> 4;

    // staging decomposition: lane -> (row-within-16, chunk)
    int sRow = lane >> 2;           // 0..15
    int sChk = lane & 3;
    int srcChunk = sChk ^ ((lane >> 3) & 3);   // pre-swizzle: dest linear

    const unsigned short* aSrc = xbf + (size_t)(m0 + wv * 16 + sRow) * K_ + srcChunk * 8;
    const unsigned short* bSrc = w0p + ((size_t)j * H_ + h0 + wv * 16 + sRow) * K_ + srcChunk * 8;
    unsigned char* ldsAw = ldsA + wv * 1024;   // + buf*16384 + i*8192
    unsigned char* ldsBw = ldsB + wv * 1024;

    // frag-read bases: byte = row*64 + ((lg ^ ((row>>1)&3))<<4); row>>1&3 == lr>>1&3
    int fx = (lg ^ ((lr >> 1) & 3)) << 4;
    const unsigned char* aF = ldsA + (wmv * 128 + lr) * 64 + fx;  // + buf*16384 + mf*1024
    const unsigned char* bF = ldsB + (wnv * 64 + lr) * 64 + fx;   // + buf*16384 + nf*1024

    f32x4 acc[8][4] = {};           // wave tile 128 x 64

#define VMW(n) do { asm volatile("s_waitcnt vmcnt(" #n ")" ::: "memory"); \
                    __builtin_amdgcn_sched_barrier(0); } while (0)
#define LGKM0() do { asm volatile("s_waitcnt lgkmcnt(0)" ::: "memory"); \
                     __builtin_amdgcn_sched_barrier(0); } while (0)
#define BAR() do { __builtin_amdgcn_s_barrier(); \
                   __builtin_amdgcn_sched_barrier(0); } while (0)
#define STG_A(tt) do { int c_ = (tt) & 3; \
    gload_lds16(aSrc + (tt) * 32,                      ldsAw + c_ * 16384); \
    gload_lds16(aSrc + (tt) * 32 + (size_t)128 * K_,   ldsAw + c_ * 16384 + 8192); } while (0)
#define STG_B(tt) do { int c_ = (tt) & 3; \
    gload_lds16(bSrc + (tt) * 32,                      ldsBw + c_ * 16384); \
    gload_lds16(bSrc + (tt) * 32 + (size_t)128 * K_,   ldsBw + c_ * 16384 + 8192); } while (0)
#define LD_A(dst, tt, mf) (dst) = *(const bf16x8*)(aF + ((tt) & 3) * 16384 + (mf) * 1024)
#define LD_B(dst, tt, nf) (dst) = *(const bf16x8*)(bF + ((tt) & 3) * 16384 + (nf) * 1024)
#define MFMAQ(mq, ar) do { __builtin_amdgcn_s_setprio(1); \
    _Pragma("unroll") for (int nf_ = 0; nf_ < 4; ++nf_) { \
      _Pragma("unroll") for (int mf_ = 0; mf_ < 4; ++mf_) \
        acc[(mq) * 4 + mf_][nf_] = __builtin_amdgcn_mfma_f32_16x16x32_bf16( \
            ar[mf_], bC[nf_], acc[(mq) * 4 + mf_][nf_], 0, 0, 0); } \
    __builtin_amdgcn_s_setprio(0); } while (0)

    // ---- prologue: stage tiles 0,1,2 (12 gloads); t0 landed after vmcnt(8) ----
    STG_A(0); STG_B(0); STG_A(1); STG_B(1); STG_A(2); STG_B(2);
    VMW(8);
    BAR();

    bf16x8 aLo[4], bC[4];
    LD_A(aLo[0], 0, 0); LD_A(aLo[1], 0, 1); LD_A(aLo[2], 0, 2); LD_A(aLo[3], 0, 3);
    LD_B(bC[0], 0, 0);  LD_B(bC[1], 0, 1);  LD_B(bC[2], 0, 2);  LD_B(bC[3], 0, 3);

    #pragma unroll
    for (int kt = 0; kt < 16; ++kt) {
        // ---------- phase 0: quadrant mq=0 ----------
        if (kt <= 12) STG_A(kt + 3);          // writes buf (kt-1)&3: readers done
        bf16x8 aHi[4];
        LD_A(aHi[0], kt, 4); LD_A(aHi[1], kt, 5);
        LD_A(aHi[2], kt, 6); LD_A(aHi[3], kt, 7);
        MFMAQ(0, aLo);                        // overlaps the aHi reads
        LGKM0();
        if (kt <= 12)      { VMW(6); }        // tile kt+1 fully landed
        else if (kt == 13) { VMW(4); }
        else if (kt == 14) { VMW(0); }
        BAR();
        // ---------- phase 1: quadrant mq=1 ----------
        if (kt <= 12) STG_B(kt + 3);
        bf16x8 aN[4], bN[4];
        if (kt < 15) {
            LD_A(aN[0], kt + 1, 0); LD_A(aN[1], kt + 1, 1);
            LD_A(aN[2], kt + 1, 2); LD_A(aN[3], kt + 1, 3);
            LD_B(bN[0], kt + 1, 0); LD_B(bN[1], kt + 1, 1);
            LD_B(bN[2], kt + 1, 2); LD_B(bN[3], kt + 1, 3);
        }
        MFMAQ(1, aHi);                        // overlaps the next-tile reads
        if (kt < 15) {
            LGKM0();
            BAR();
            aLo[0] = aN[0]; aLo[1] = aN[1]; aLo[2] = aN[2]; aLo[3] = aN[3];
            bC[0] = bN[0];  bC[1] = bN[1];  bC[2] = bN[2];  bC[3] = bN[3];
        }
    }

    // ---- fused epilogue: h = leaky(acc + b0); partial mu = h . W1 ----
    float b0v[4], w1v[4];
    #pragma unroll
    for (int nf = 0; nf < 4; ++nf) {
        int col = h0 + (wnv << 6) + (nf << 4) + lr;
        b0v[nf] = b0[(size_t)j * H_ + col];
        w1v[nf] = W1[(size_t)j * H_ + col];
    }
    #pragma unroll
    for (int mf = 0; mf < 8; ++mf) {
        #pragma unroll
        for (int rg = 0; rg < 4; ++rg) {
            float ps = 0.f;
            #pragma unroll
            for (int nf = 0; nf < 4; ++nf) {
                float hv = acc[mf][nf][rg] + b0v[nf];  // C/D: col=lr, row=lg*4+rg
                hv = hv > 0.f ? hv : 0.01f * hv;
                ps += hv * w1v[nf];
            }
            ps += __shfl_xor(ps, 1);
            ps += __shfl_xor(ps, 2);
            ps += __shfl_xor(ps, 4);
            ps += __shfl_xor(ps, 8);
            if (lr == 0) {
                int row = m0 + (wmv << 7) + (mf << 4) + (lg << 2) + rg;
                atomicAdd(out + (size_t)row * J_ + j, ps);
            }
        }
    }
#undef VMW
#undef LGKM0
#undef BAR
#undef STG_A
#undef STG_B
#undef LD_A
#undef LD_B
#undef MFMAQ
}

// Fallback (ws too small): on-the-fly mask*W0 cvt staging (round-2 proven).
__global__ __launch_bounds__(256, 2) void enc_kernel_fb(
    const unsigned short* __restrict__ xbf,
    const float* __restrict__ W0,
    const float* __restrict__ wmask,
    const int* __restrict__ ip,
    const float* __restrict__ b0,
    const float* __restrict__ W1,
    float* __restrict__ out) {
    __shared__ unsigned char ldsA[128 * 128];
    __shared__ unsigned char ldsB[128 * 128];

    int p = blockIdx.x;
    int xcd = p & 7;
    int q = p >> 3;
    int j = (xcd << 5) + (q >> 5);
    int inner = q & 31;
    int m0 = (inner >> 2) << 7;
    int h0 = (inner & 3) << 7;

    int i = ip[0];
    const float* w0j = W0 + (size_t)j * (H_ * K_);
    const float* wij = wmask + ((size_t)i * J_ + j) * K_;

    int tid = threadIdx.x;
    int lane = tid & 63;
    int wv = tid >> 6;
    int wm = wv >> 1, wn = wv & 1;
    int lr = lane & 15, lg = lane >> 4;
    int srow0 = tid >> 3;
    int c = tid & 7;

    f32x4 acc[4][4] = {};

    for (int ks = 0; ks < K_ / 64; ++ks) {
        int k0 = ks * 64;
        #pragma unroll
        for (int it = 0; it < 4; ++it) {
            int r = srow0 + it * 32;
            u32x4 v = *(const u32x4*)(xbf + (size_t)(m0 + r) * K_ + k0 + c * 8);
            *(u32x4*)(ldsA + r * 128 + ((c * 16) ^ ((r & 7) << 4))) = v;
        }
        f32x4 s0 = *(const f32x4*)(wij + k0 + c * 8);
        f32x4 s1 = *(const f32x4*)(wij + k0 + c * 8 + 4);
        #pragma unroll
        for (int it = 0; it < 4; ++it) {
            int hr = srow0 + it * 32;
            const float* src = w0j + (size_t)(h0 + hr) * K_ + k0 + c * 8;
            f32x4 a0 = *(const f32x4*)(src);
            f32x4 a1 = *(const f32x4*)(src + 4);
            a0 *= s0; a1 *= s1;
            u16x8 bvv;
            #pragma unroll
            for (int e = 0; e < 4; ++e) { bvv[e] = f2bf(a0[e]); bvv[e + 4] = f2bf(a1[e]); }
            *(u16x8*)(ldsB + hr * 128 + ((c * 16) ^ ((hr & 7) << 4))) = bvv;
        }
        __syncthreads();
        #pragma unroll
        for (int kf = 0; kf < 2; ++kf) {
            bf16x8 af[4], bfr[4];
            #pragma unroll
            for (int mf = 0; mf < 4; ++mf) {
                int r = (wm << 6) + (mf << 4) + lr;
                af[mf] = *(const bf16x8*)(ldsA + r * 128 +
                          (((kf << 6) + (lg << 4)) ^ ((r & 7) << 4)));
            }
            #pragma unroll
            for (int nf = 0; nf < 4; ++nf) {
                int hrw = (wn << 6) + (nf << 4) + lr;
                bfr[nf] = *(const bf16x8*)(ldsB + hrw * 128 +
                          (((kf << 6) + (lg << 4)) ^ ((hrw & 7) << 4)));
            }
            #pragma unroll
            for (int mf = 0; mf < 4; ++mf)
                #pragma unroll
                for (int nf = 0; nf < 4; ++nf)
                    acc[mf][nf] = __builtin_amdgcn_mfma_f32_16x16x32_bf16(
                        af[mf], bfr[nf], acc[mf][nf], 0, 0, 0);
        }
        __syncthreads();
    }

    float b0v[4], w1v[4];
    #pragma unroll
    for (int nf = 0; nf < 4; ++nf) {
        int h = h0 + (wn << 6) + (nf << 4) + lr;
        b0v[nf] = b0[(size_t)j * H_ + h];
        w1v[nf] = W1[(size_t)j * H_ + h];
    }
    #pragma unroll
    for (int mf = 0; mf < 4; ++mf) {
        #pragma unroll
        for (int rg = 0; rg < 4; ++rg) {
            float ps = 0.f;
            #pragma unroll
            for (int nf = 0; nf < 4; ++nf) {
                float hv = acc[mf][nf][rg] + b0v[nf];
                hv = hv > 0.f ? hv : 0.01f * hv;
                ps += hv * w1v[nf];
            }
            ps += __shfl_xor(ps, 1);
            ps += __shfl_xor(ps, 2);
            ps += __shfl_xor(ps, 4);
            ps += __shfl_xor(ps, 8);
            if (lr == 0) {
                int row = m0 + (wm << 6) + (mf << 4) + (lg << 2) + rg;
                atomicAdd(out + (size_t)row * J_ + j, ps);
            }
        }
    }
}

extern "C" void kernel_launch(void* const* d_in, const int* in_sizes, int n_in,
                              void* d_out, int out_size, void* d_ws, size_t ws_size,
                              hipStream_t stream) {
    const float* x      = (const float*)d_in[0];
    const int*   ip     = (const int*)d_in[1];
    const float* wmask  = (const float*)d_in[2];
    const float* W0     = (const float*)d_in[3];
    const float* b0     = (const float*)d_in[4];
    const float* W1     = (const float*)d_in[5];
    const float* b1     = (const float*)d_in[6];
    const float* logvar = (const float*)d_in[7];
    float* out = (float*)d_out;
    unsigned short* xbf = (unsigned short*)d_ws;          // 1 MB
    const size_t xbf_elems = (size_t)B_ * K_;
    const size_t w0p_bytes = (size_t)J_ * H_ * K_ * 2;    // 134.2 MB
    const size_t need = xbf_elems * 2 + w0p_bytes;

    prep_kernel<<<512, 256, 0, stream>>>(x, b1, logvar, xbf, out);
    if (ws_size >= need) {
        unsigned short* w0p = xbf + xbf_elems;
        wprep_kernel<<<32768, 256, 0, stream>>>(W0, wmask, ip, w0p);
        enc_kernel<<<2048, 512, 0, stream>>>(xbf, w0p, b0, W1, out);
    } else {
        enc_kernel_fb<<<8192, 256, 0, stream>>>(xbf, W0, wmask, ip, b0, W1, out);
    }
}

// Round 7
// 580.764 us; speedup vs baseline: 1.0267x; 1.0267x over previous
//
#include <hip/hip_runtime.h>

// Problem constants (from reference): D=4, J=256, K=512, H=512, B=1024
#define J_ 256
#define K_ 512
#define H_ 512
#define B_ 1024

typedef float f32x4 __attribute__((ext_vector_type(4)));
typedef unsigned int u32x4 __attribute__((ext_vector_type(4)));
typedef unsigned short u16x4 __attribute__((ext_vector_type(4)));
typedef unsigned short u16x8 __attribute__((ext_vector_type(8)));
typedef __bf16 bf16x8 __attribute__((ext_vector_type(8)));

// f32 -> bf16 round-to-nearest-even (manual; inputs are finite)
__device__ __forceinline__ unsigned short f2bf(float f) {
    unsigned int u = __float_as_uint(f);
    u += 0x7fffu + ((u >> 16) & 1u);
    return (unsigned short)(u >> 16);
}

// async global->LDS, 16B per lane; LDS dest is wave-uniform base + lane*16
__device__ __forceinline__ void gload_lds16(const void* g, void* l) {
    __builtin_amdgcn_global_load_lds(
        (const __attribute__((address_space(1))) unsigned int*)g,
        (__attribute__((address_space(3))) unsigned int*)l, 16, 0, 0);
}

// Prep: x f32 -> bf16 into ws; init out: mu[b,j] = b1[j]; logvar tail.
__global__ __launch_bounds__(256) void prep_kernel(
    const float* __restrict__ x, const float* __restrict__ b1,
    const float* __restrict__ logvar, unsigned short* __restrict__ xbf,
    float* __restrict__ out) {
    int t = blockIdx.x * 256 + threadIdx.x;
    {
        f32x4 v = *(const f32x4*)(x + (size_t)t * 4);
        u16x4 o;
        o[0] = f2bf(v[0]); o[1] = f2bf(v[1]); o[2] = f2bf(v[2]); o[3] = f2bf(v[3]);
        *(u16x4*)(xbf + (size_t)t * 4) = o;
    }
    if (t < (B_ * J_) / 4) {
        int b = t >> 6;
        int j4 = (t & 63) << 2;
        f32x4 bb = *(const f32x4*)(b1 + j4);
        *(f32x4*)(out + ((size_t)b << 8) + j4) = bb;
    }
    if (t < 4) out[B_ * J_ + t] = logvar[t];
}

// W0' = bf16(W0 * wi), memory-bound pass.
__global__ __launch_bounds__(256) void wprep_kernel(
    const float* __restrict__ W0, const float* __restrict__ wmask,
    const int* __restrict__ ip, unsigned short* __restrict__ w0p) {
    size_t t = (size_t)blockIdx.x * 256 + threadIdx.x;
    size_t e = t * 8;
    int j = (int)(e >> 18);               // H*K = 262144 elems per j
    int k = (int)(e & (K_ - 1));
    const float* wi = wmask + ((size_t)ip[0] * J_ + j) * K_ + k;
    f32x4 s0 = *(const f32x4*)wi;
    f32x4 s1 = *(const f32x4*)(wi + 4);
    f32x4 a0 = *(const f32x4*)(W0 + e);
    f32x4 a1 = *(const f32x4*)(W0 + e + 4);
    a0 *= s0; a1 *= s1;
    u16x8 o;
    #pragma unroll
    for (int q = 0; q < 4; ++q) { o[q] = f2bf(a0[q]); o[q + 4] = f2bf(a1[q]); }
    *(u16x8*)(w0p + e) = o;
}

// m201-faithful 8-phase 256x256 grouped GEMM. BK=64 (8 K-tiles), 512 thr =
// 8 waves (2M x 4N), wave tile 128x64. LDS 128KB = 2buf x 2half x 128x64 x
// 2(A,B) x 2B. Per phase: {ds-read subtile | stage 1 half-tile (2 gloads) |
// bar | lgkm0 | 16 MFMA (one C-quadrant) | bar}. vmcnt(4) once per K-tile
// (never 0 in steady state). Grid 2048 = j(256) x mb(4) x nb(2), XCD-swizzled.
__global__ __launch_bounds__(512, 2) void enc_kernel(
    const unsigned short* __restrict__ xbf,
    const unsigned short* __restrict__ w0p,
    const float* __restrict__ b0,
    const float* __restrict__ W1,
    float* __restrict__ out) {
    // A at 0, B at 65536; offset = buf*32768 + half*16384 + row*128 + chunk*16
    __shared__ unsigned char lds[131072];

    int p = blockIdx.x;
    int xcd = p & 7;
    int t = p >> 3;                 // 0..255
    int j = (xcd << 5) + (t >> 3);
    int inner = t & 7;
    int m0 = (inner >> 1) << 8;     // 0,256,512,768
    int h0 = (inner & 1) << 8;      // 0,256

    int tid = threadIdx.x;
    int lane = tid & 63;
    int wv = tid >> 6;              // 0..7
    int wm = wv >> 2;               // M-wave 0..1 (128 rows each)
    int wnv = wv & 3;               // N-wave 0..3 (64 cols each)
    int lr = lane & 15, lg = lane >> 4;
    int cBase = lg ^ (lr & 7);      // read-side chunk base (XOR swizzle)
    int sRow = lane >> 3;           // staging row within an 8-row group
    int sCh = (lane & 7) ^ sRow;    // staging source chunk (dest linear)

    const unsigned short* aLane = xbf + (size_t)(m0 + sRow) * K_ + sCh * 8;
    const unsigned short* bLane = w0p + ((size_t)j * H_ + h0 + sRow) * K_ + sCh * 8;

    const unsigned char* aRd = lds + wm * 16384 + lr * 128;
    const unsigned char* bRd = lds + 65536 + (wnv >> 1) * 16384 +
                               ((wnv & 1) * 64 + lr) * 128;

#define VMW(n) do { asm volatile("s_waitcnt vmcnt(" #n ")" ::: "memory"); \
                    __builtin_amdgcn_sched_barrier(0); } while (0)
#define LGKM(n) do { asm volatile("s_waitcnt lgkmcnt(" #n ")" ::: "memory"); \
                     __builtin_amdgcn_sched_barrier(0); } while (0)
#define BAR() do { __builtin_amdgcn_s_barrier(); \
                   __builtin_amdgcn_sched_barrier(0); } while (0)
// stage one half-tile (128 rows x 64 k): 2 gloads/wave x 8 waves = 16 KB
#define STG_A(bf, hf, kk) do { \
    gload_lds16(aLane + (size_t)((hf) * 128 + wv * 8) * K_ + (kk) * 64, \
                lds + (bf) * 32768 + (hf) * 16384 + wv * 1024); \
    gload_lds16(aLane + (size_t)((hf) * 128 + 64 + wv * 8) * K_ + (kk) * 64, \
                lds + (bf) * 32768 + (hf) * 16384 + 8192 + wv * 1024); } while (0)
#define STG_B(bf, hf, kk) do { \
    gload_lds16(bLane + (size_t)((hf) * 128 + wv * 8) * K_ + (kk) * 64, \
                lds + 65536 + (bf) * 32768 + (hf) * 16384 + wv * 1024); \
    gload_lds16(bLane + (size_t)((hf) * 128 + 64 + wv * 8) * K_ + (kk) * 64, \
                lds + 65536 + (bf) * 32768 + (hf) * 16384 + 8192 + wv * 1024); } while (0)
#define LDA(dst, bf, qm, mf, kf) (dst) = *(const bf16x8*)(aRd + (bf) * 32768 + \
    ((qm) * 64 + (mf) * 16) * 128 + ((cBase ^ ((kf) << 2)) << 4))
#define LDB(dst, bf, pp, nf, kf) (dst) = *(const bf16x8*)(bRd + (bf) * 32768 + \
    ((pp) * 32 + (nf) * 16) * 128 + ((cBase ^ ((kf) << 2)) << 4))
#define MFMA_Q(qm, qn, aR, bR) do { \
    __builtin_amdgcn_s_setprio(1); \
    _Pragma("unroll") for (int kf_ = 0; kf_ < 2; ++kf_) \
      _Pragma("unroll") for (int mf_ = 0; mf_ < 4; ++mf_) \
        _Pragma("unroll") for (int nf_ = 0; nf_ < 2; ++nf_) \
          acc[(qm) * 4 + mf_][(qn) * 2 + nf_] = \
              __builtin_amdgcn_mfma_f32_16x16x32_bf16( \
                  aR[kf_][mf_], bR[kf_][nf_], acc[(qm) * 4 + mf_][(qn) * 2 + nf_], 0, 0, 0); \
    __builtin_amdgcn_s_setprio(0); } while (0)

    f32x4 acc[8][4] = {};           // wave tile 128(m) x 64(h)
    bf16x8 aC[2][4], bL[2][2], bH[2][2];

    // ---- prologue: tile0 (4 halves) + tile1 {B-lo, A-lo}; vmcnt(4) -> tile0 in ----
    STG_A(0, 0, 0); STG_A(0, 1, 0); STG_B(0, 0, 0); STG_B(0, 1, 0);
    STG_B(1, 0, 1); STG_A(1, 0, 1);
    VMW(4); BAR();

    #pragma unroll
    for (int kt = 0; kt < 8; ++kt) {
        const int bf = kt & 1, bn = bf ^ 1;
        // ---- ph0: reads A-quad-lo(8) + B-pair-lo(4); stage A-hi(kt+1) ----
        LDA(aC[0][0], bf, 0, 0, 0); LDA(aC[0][1], bf, 0, 1, 0);
        LDA(aC[0][2], bf, 0, 2, 0); LDA(aC[0][3], bf, 0, 3, 0);
        LDA(aC[1][0], bf, 0, 0, 1); LDA(aC[1][1], bf, 0, 1, 1);
        LDA(aC[1][2], bf, 0, 2, 1); LDA(aC[1][3], bf, 0, 3, 1);
        LDB(bL[0][0], bf, 0, 0, 0); LDB(bL[0][1], bf, 0, 1, 0);
        LDB(bL[1][0], bf, 0, 0, 1); LDB(bL[1][1], bf, 0, 1, 1);
        if (kt < 7) STG_A(bn, 1, kt + 1);
        LGKM(8);
        BAR(); LGKM(0);
        MFMA_Q(0, 0, aC, bL);
        BAR();
        // ---- ph1: reads B-pair-hi(4); stage B-hi(kt+1) ----
        LDB(bH[0][0], bf, 1, 0, 0); LDB(bH[0][1], bf, 1, 1, 0);
        LDB(bH[1][0], bf, 1, 0, 1); LDB(bH[1][1], bf, 1, 1, 1);
        if (kt < 7) STG_B(bn, 1, kt + 1);
        BAR(); LGKM(0);
        MFMA_Q(0, 1, aC, bH);
        BAR();
        // ---- ph2: reads A-quad-hi(8); stage B-lo(kt+2) ----
        LDA(aC[0][0], bf, 1, 0, 0); LDA(aC[0][1], bf, 1, 1, 0);
        LDA(aC[0][2], bf, 1, 2, 0); LDA(aC[0][3], bf, 1, 3, 0);
        LDA(aC[1][0], bf, 1, 0, 1); LDA(aC[1][1], bf, 1, 1, 1);
        LDA(aC[1][2], bf, 1, 2, 1); LDA(aC[1][3], bf, 1, 3, 1);
        if (kt < 6) STG_B(bf, 0, kt + 2);
        BAR(); LGKM(0);
        MFMA_Q(1, 0, aC, bL);
        BAR();
        // ---- ph3: no reads; stage A-lo(kt+2); counted vmcnt once per K-tile ----
        if (kt < 6) STG_A(bf, 0, kt + 2);
        if (kt < 6)      { VMW(4); }   // tile kt+1 fully landed; 2 halves in flight
        else if (kt == 6) { VMW(0); }  // tail drain: tile 7 landed
        BAR();
        MFMA_Q(1, 1, aC, bH);
        BAR();
    }

    // ---- fused epilogue: h = leaky(acc + b0); partial mu = h . W1 ----
    float b0v[4], w1v[4];
    #pragma unroll
    for (int nf = 0; nf < 4; ++nf) {
        int col = h0 + (wnv << 6) + (nf << 4) + lr;
        b0v[nf] = b0[(size_t)j * H_ + col];
        w1v[nf] = W1[(size_t)j * H_ + col];
    }
    #pragma unroll
    for (int mf = 0; mf < 8; ++mf) {
        #pragma unroll
        for (int rg = 0; rg < 4; ++rg) {
            float ps = 0.f;
            #pragma unroll
            for (int nf = 0; nf < 4; ++nf) {
                float hv = acc[mf][nf][rg] + b0v[nf];  // C/D: col=lr, row=lg*4+rg
                hv = hv > 0.f ? hv : 0.01f * hv;
                ps += hv * w1v[nf];
            }
            ps += __shfl_xor(ps, 1);
            ps += __shfl_xor(ps, 2);
            ps += __shfl_xor(ps, 4);
            ps += __shfl_xor(ps, 8);
            if (lr == 0) {
                int row = m0 + (wm << 7) + (mf << 4) + (lg << 2) + rg;
                atomicAdd(out + (size_t)row * J_ + j, ps);
            }
        }
    }
#undef VMW
#undef LGKM
#undef BAR
#undef STG_A
#undef STG_B
#undef LDA
#undef LDB
#undef MFMA_Q
}

// Fallback (ws too small): on-the-fly mask*W0 cvt staging (round-2 proven).
__global__ __launch_bounds__(256, 2) void enc_kernel_fb(
    const unsigned short* __restrict__ xbf,
    const float* __restrict__ W0,
    const float* __restrict__ wmask,
    const int* __restrict__ ip,
    const float* __restrict__ b0,
    const float* __restrict__ W1,
    float* __restrict__ out) {
    __shared__ unsigned char ldsA[128 * 128];
    __shared__ unsigned char ldsB[128 * 128];

    int p = blockIdx.x;
    int xcd = p & 7;
    int q = p >> 3;
    int j = (xcd << 5) + (q >> 5);
    int inner = q & 31;
    int m0 = (inner >> 2) << 7;
    int h0 = (inner & 3) << 7;

    int i = ip[0];
    const float* w0j = W0 + (size_t)j * (H_ * K_);
    const float* wij = wmask + ((size_t)i * J_ + j) * K_;

    int tid = threadIdx.x;
    int lane = tid & 63;
    int wv = tid >> 6;
    int wm = wv >> 1, wn = wv & 1;
    int lr = lane & 15, lg = lane >> 4;
    int srow0 = tid >> 3;
    int c = tid & 7;

    f32x4 acc[4][4] = {};

    for (int ks = 0; ks < K_ / 64; ++ks) {
        int k0 = ks * 64;
        #pragma unroll
        for (int it = 0; it < 4; ++it) {
            int r = srow0 + it * 32;
            u32x4 v = *(const u32x4*)(xbf + (size_t)(m0 + r) * K_ + k0 + c * 8);
            *(u32x4*)(ldsA + r * 128 + ((c * 16) ^ ((r & 7) << 4))) = v;
        }
        f32x4 s0 = *(const f32x4*)(wij + k0 + c * 8);
        f32x4 s1 = *(const f32x4*)(wij + k0 + c * 8 + 4);
        #pragma unroll
        for (int it = 0; it < 4; ++it) {
            int hr = srow0 + it * 32;
            const float* src = w0j + (size_t)(h0 + hr) * K_ + k0 + c * 8;
            f32x4 a0 = *(const f32x4*)(src);
            f32x4 a1 = *(const f32x4*)(src + 4);
            a0 *= s0; a1 *= s1;
            u16x8 bvv;
            #pragma unroll
            for (int e = 0; e < 4; ++e) { bvv[e] = f2bf(a0[e]); bvv[e + 4] = f2bf(a1[e]); }
            *(u16x8*)(ldsB + hr * 128 + ((c * 16) ^ ((hr & 7) << 4))) = bvv;
        }
        __syncthreads();
        #pragma unroll
        for (int kf = 0; kf < 2; ++kf) {
            bf16x8 af[4], bfr[4];
            #pragma unroll
            for (int mf = 0; mf < 4; ++mf) {
                int r = (wm << 6) + (mf << 4) + lr;
                af[mf] = *(const bf16x8*)(ldsA + r * 128 +
                          (((kf << 6) + (lg << 4)) ^ ((r & 7) << 4)));
            }
            #pragma unroll
            for (int nf = 0; nf < 4; ++nf) {
                int hrw = (wn << 6) + (nf << 4) + lr;
                bfr[nf] = *(const bf16x8*)(ldsB + hrw * 128 +
                          (((kf << 6) + (lg << 4)) ^ ((hrw & 7) << 4)));
            }
            #pragma unroll
            for (int mf = 0; mf < 4; ++mf)
                #pragma unroll
                for (int nf = 0; nf < 4; ++nf)
                    acc[mf][nf] = __builtin_amdgcn_mfma_f32_16x16x32_bf16(
                        af[mf], bfr[nf], acc[mf][nf], 0, 0, 0);
        }
        __syncthreads();
    }

    float b0v[4], w1v[4];
    #pragma unroll
    for (int nf = 0; nf < 4; ++nf) {
        int h = h0 + (wn << 6) + (nf << 4) + lr;
        b0v[nf] = b0[(size_t)j * H_ + h];
        w1v[nf] = W1[(size_t)j * H_ + h];
    }
    #pragma unroll
    for (int mf = 0; mf < 4; ++mf) {
        #pragma unroll
        for (int rg = 0; rg < 4; ++rg) {
            float ps = 0.f;
            #pragma unroll
            for (int nf = 0; nf < 4; ++nf) {
                float hv = acc[mf][nf][rg] + b0v[nf];
                hv = hv > 0.f ? hv : 0.01f * hv;
                ps += hv * w1v[nf];
            }
            ps += __shfl_xor(ps, 1);
            ps += __shfl_xor(ps, 2);
            ps += __shfl_xor(ps, 4);
            ps += __shfl_xor(ps, 8);
            if (lr == 0) {
                int row = m0 + (wm << 6) + (mf << 4) + (lg << 2) + rg;
                atomicAdd(out + (size_t)row * J_ + j, ps);
            }
        }
    }
}

extern "C" void kernel_launch(void* const* d_in, const int* in_sizes, int n_in,
                              void* d_out, int out_size, void* d_ws, size_t ws_size,
                              hipStream_t stream) {
    const float* x      = (const float*)d_in[0];
    const int*   ip     = (const int*)d_in[1];
    const float* wmask  = (const float*)d_in[2];
    const float* W0     = (const float*)d_in[3];
    const float* b0     = (const float*)d_in[4];
    const float* W1     = (const float*)d_in[5];
    const float* b1     = (const float*)d_in[6];
    const float* logvar = (const float*)d_in[7];
    float* out = (float*)d_out;
    unsigned short* xbf = (unsigned short*)d_ws;          // 1 MB
    const size_t xbf_elems = (size_t)B_ * K_;
    const size_t w0p_bytes = (size_t)J_ * H_ * K_ * 2;    // 134.2 MB
    const size_t need = xbf_elems * 2 + w0p_bytes;

    prep_kernel<<<512, 256, 0, stream>>>(x, b1, logvar, xbf, out);
    if (ws_size >= need) {
        unsigned short* w0p = xbf + xbf_elems;
        wprep_kernel<<<32768, 256, 0, stream>>>(W0, wmask, ip, w0p);
        enc_kernel<<<2048, 512, 0, stream>>>(xbf, w0p, b0, W1, out);
    } else {
        enc_kernel_fb<<<8192, 256, 0, stream>>>(xbf, W0, wmask, ip, b0, W1, out);
    }
}